// Round 9
// baseline (1258.615 us; speedup 1.0000x reference)
//
#include <hip/hip_runtime.h>
#include <hip/hip_bf16.h>

#define NU 100000
#define NM 20000
#define DD 64
#define RR 5
#define EE 400000
#define NE (RR * EE)            // 2,000,000 edges per direction
#define NNODE (NM + NU)         // 120,000 destination bins (movies first)
#define NTILE (EE / 16)         // 25,000 16-edge tiles per relation
#define TPW 25                  // tiles per wave: 25000 = 4 waves * 25 * 250 blocks
#define GM_BLOCKS (NM / 4)      // 5000 movie-gather blocks (4 movies/block)
#define GU_BLOCKS (NU / 32)     // 3125 user-gather blocks (32 users/block)

typedef __attribute__((ext_vector_type(8))) short bf16x8;
typedef __attribute__((ext_vector_type(8))) short s16x8;
typedef __attribute__((ext_vector_type(4))) float f32x4;

static __device__ __forceinline__ short f2bf(float f) {
  return __builtin_bit_cast(short, __float2bfloat16(f));
}
static __device__ __forceinline__ float bf2f(short s) {
  return __builtin_bit_cast(float, ((unsigned)(unsigned short)s) << 16);
}

static __device__ __forceinline__ bf16x8 pack8(const float4 a, const float4 b) {
  bf16x8 o;
  o[0] = f2bf(a.x); o[1] = f2bf(a.y); o[2] = f2bf(a.z); o[3] = f2bf(a.w);
  o[4] = f2bf(b.x); o[5] = f2bf(b.y); o[6] = f2bf(b.z); o[7] = f2bf(b.w);
  return o;
}
static __device__ __forceinline__ bf16x8 cvt8(const float* __restrict__ p) {
  return pack8(*(const float4*)p, *(const float4*)(p + 4));
}

static __device__ __forceinline__ float sigm(float x) { return 1.f / (1.f + __expf(-x)); }
static __device__ __forceinline__ float gelu(float x) {
  return 0.5f * x * (1.f + erff(x * 0.70710678118654752f));
}

// ---------------------------------------------------------------------------
// rank0: ONE atomic pass. cnt (zeroed) -> per-edge rank within destination,
// and cnt ends up holding the per-node degree (input to scanoff).
// ---------------------------------------------------------------------------
__global__ __launch_bounds__(256) void rank0_k(const int* __restrict__ eu,
                                               const int* __restrict__ em,
                                               int* __restrict__ cnt,
                                               int* __restrict__ rank_m,
                                               int* __restrict__ rank_u) {
  const int i = (blockIdx.x * 256 + threadIdx.x) * 4;
  if (i < NE) {
    const int4 a = *(const int4*)(em + i);
    const int4 b = *(const int4*)(eu + i);
    int4 rm, ru;
    rm.x = atomicAdd(&cnt[a.x], 1);
    rm.y = atomicAdd(&cnt[a.y], 1);
    rm.z = atomicAdd(&cnt[a.z], 1);
    rm.w = atomicAdd(&cnt[a.w], 1);
    ru.x = atomicAdd(&cnt[NM + b.x], 1);
    ru.y = atomicAdd(&cnt[NM + b.y], 1);
    ru.z = atomicAdd(&cnt[NM + b.z], 1);
    ru.w = atomicAdd(&cnt[NM + b.w], 1);
    *(int4*)(rank_m + i) = rm;
    *(int4*)(rank_u + i) = ru;
  }
}

__global__ __launch_bounds__(1024) void scanoff_k(const int* __restrict__ cnt,
                                                  int* __restrict__ off) {
  __shared__ int sums[1024];
  const int t = threadIdx.x;
  const int ch = (NNODE + 1023) >> 10;    // 118
  const int b0 = t * ch;
  int s = 0;
  for (int i = 0; i < ch; ++i) { int idx = b0 + i; if (idx < NNODE) s += cnt[idx]; }
  sums[t] = s;
  __syncthreads();
  for (int d = 1; d < 1024; d <<= 1) {
    int x = (t >= d) ? sums[t - d] : 0;
    __syncthreads();
    sums[t] += x;
    __syncthreads();
  }
  int run = (t > 0) ? sums[t - 1] : 0;
  for (int i = 0; i < ch; ++i) {
    int idx = b0 + i;
    if (idx < NNODE) { off[idx] = run; run += cnt[idx]; }
  }
  if (t == 1023) off[NNODE] = sums[1023];
}

// ---------------------------------------------------------------------------
// Main fused MFMA kernel — flat r3/r4 schedule (best measured: 394us).
// Per 16-edge tile: both directions' messages via one MFMA pass, stored (bf16)
// at slot = off[dst] + rank.  Column permutation: tile t, col c -> dim 4c+t.
// Grid (250, RR); 25 tiles/wave -> 1250 blocks = one resident generation.
// ---------------------------------------------------------------------------
__global__ __launch_bounds__(256, 5) void gcmc_main(
    const int* __restrict__ edges_u, const int* __restrict__ edges_m,
    const float* __restrict__ rfeat,
    const float* __restrict__ W_user, const float* __restrict__ W_movie,
    const float* __restrict__ ps_u, const float* __restrict__ rs_u, const float* __restrict__ rw_u,
    const float* __restrict__ ps_m, const float* __restrict__ rs_m, const float* __restrict__ rw_m,
    const float* __restrict__ user_cj, const float* __restrict__ movie_cj,
    const int* __restrict__ rank_m, const int* __restrict__ rank_u,
    const int* __restrict__ off,
    short* __restrict__ msg)
{
  const int r    = blockIdx.y;
  const int lane = threadIdx.x & 63;
  const int wid  = threadIdx.x >> 6;
  const int c    = lane & 15;
  const int kr   = lane >> 4;
  const int wtile = blockIdx.x * 4 + wid;       // wave id in [0, 1000)

  // ---- B fragments in registers (bf16), loaded once per wave ----
  bf16x8 Bu[4][2], Bm[4][2], Bs[2];
#pragma unroll
  for (int t = 0; t < 4; ++t) {
#pragma unroll
    for (int s = 0; s < 2; ++s) {
      Bu[t][s] = cvt8(rw_u + ((size_t)r * DD + (4 * c + t)) * DD + s * 32 + kr * 8);
      Bm[t][s] = cvt8(rw_m + ((size_t)r * DD + (4 * c + t)) * DD + s * 32 + kr * 8);
    }
  }
#pragma unroll
  for (int s = 0; s < 2; ++s) {
    if (c < 4) {
      const float* v = (c == 0 ? rs_u : c == 1 ? ps_u : c == 2 ? rs_m : ps_m)
                       + r * DD + s * 32 + kr * 8;
      Bs[s] = cvt8(v);
    } else {
      bf16x8 z = {0, 0, 0, 0, 0, 0, 0, 0};
      Bs[s] = z;
    }
  }

#pragma unroll 1
  for (int tt = 0; tt < TPW; ++tt) {
    const int tile = wtile * TPW + tt;
    const int e0 = tile * 16;

    // ---- A raw loads ----
    const float* arow = rfeat + ((size_t)r * EE + e0 + c) * DD + kr * 8;
    const float4 fa0 = *(const float4*)arow;
    const float4 fa1 = *(const float4*)(arow + 4);
    const float4 fa2 = *(const float4*)(arow + 32);
    const float4 fa3 = *(const float4*)(arow + 36);

    // ---- edge / rank loads: this lane's 4 rows are consecutive -> int4 ----
    const int ebase = r * EE + e0 + kr * 4;
    const int4 eu4  = *(const int4*)(edges_u + ebase);
    const int4 em4  = *(const int4*)(edges_m + ebase);
    const int4 rm4  = *(const int4*)(rank_m + ebase);
    const int4 ru4  = *(const int4*)(rank_u + ebase);
    const int eus[4] = {eu4.x, eu4.y, eu4.z, eu4.w};
    const int ems[4] = {em4.x, em4.y, em4.z, em4.w};
    const int rms[4] = {rm4.x, rm4.y, rm4.z, rm4.w};
    const int rus[4] = {ru4.x, ru4.y, ru4.z, ru4.w};

    // ---- dependent gathers, all issued up-front ----
    int slm[4], slu[4];
    float cju[4], cjm[4];
    float4 hu[4], hm[4];
#pragma unroll
    for (int q = 0; q < 4; ++q) {
      slm[q] = off[ems[q]] + rms[q];
      slu[q] = off[NM + eus[q]] + rus[q];
      cju[q] = user_cj[eus[q]];
      cjm[q] = movie_cj[ems[q]];
      hu[q]  = *(const float4*)(W_user  + ((size_t)r * NU + eus[q]) * DD + 4 * c);
      hm[q]  = *(const float4*)(W_movie + ((size_t)r * NM + ems[q]) * DD + 4 * c);
    }

    // ---- MFMA ----
    const bf16x8 A0 = pack8(fa0, fa1);
    const bf16x8 A1 = pack8(fa2, fa3);
    f32x4 z4 = {0.f, 0.f, 0.f, 0.f};
    f32x4 Cu[4], Cm[4], Cs;
#pragma unroll
    for (int t = 0; t < 4; ++t) { Cu[t] = z4; Cm[t] = z4; }
    Cs = z4;
#pragma unroll
    for (int t = 0; t < 4; ++t) {
      Cu[t] = __builtin_amdgcn_mfma_f32_16x16x32_bf16(A0, Bu[t][0], Cu[t], 0, 0, 0);
      Cu[t] = __builtin_amdgcn_mfma_f32_16x16x32_bf16(A1, Bu[t][1], Cu[t], 0, 0, 0);
      Cm[t] = __builtin_amdgcn_mfma_f32_16x16x32_bf16(A0, Bm[t][0], Cm[t], 0, 0, 0);
      Cm[t] = __builtin_amdgcn_mfma_f32_16x16x32_bf16(A1, Bm[t][1], Cm[t], 0, 0, 0);
    }
    Cs = __builtin_amdgcn_mfma_f32_16x16x32_bf16(A0, Bs[0], Cs, 0, 0, 0);
    Cs = __builtin_amdgcn_mfma_f32_16x16x32_bf16(A1, Bs[1], Cs, 0, 0, 0);

    // ---- combine + store ----
#pragma unroll
    for (int q = 0; q < 4; ++q) {
      const int src = (lane & 48);
      const float su = __shfl(Cs[q], src);
      const float pu = __shfl(Cs[q], src | 1);
      const float sm = __shfl(Cs[q], src | 2);
      const float pm = __shfl(Cs[q], src | 3);
      const float sgu = sigm(su), pau = sigm(pu);
      const float sgm_ = sigm(sm), pam = sigm(pm);

      short4 vm, vu;
      vm.x = f2bf((hu[q].x * pau + Cu[0][q] * sgu) * cju[q]);
      vm.y = f2bf((hu[q].y * pau + Cu[1][q] * sgu) * cju[q]);
      vm.z = f2bf((hu[q].z * pau + Cu[2][q] * sgu) * cju[q]);
      vm.w = f2bf((hu[q].w * pau + Cu[3][q] * sgu) * cju[q]);
      vu.x = f2bf((hm[q].x * pam + Cm[0][q] * sgm_) * cjm[q]);
      vu.y = f2bf((hm[q].y * pam + Cm[1][q] * sgm_) * cjm[q]);
      vu.z = f2bf((hm[q].z * pam + Cm[2][q] * sgm_) * cjm[q]);
      vu.w = f2bf((hm[q].w * pam + Cm[3][q] * sgm_) * cjm[q]);

      *(short4*)(msg + ((size_t)slm[q] << 6) + 4 * c) = vm;
      *(short4*)(msg + ((size_t)slu[q] << 6) + 4 * c) = vu;
    }
  }
}

// ---------------------------------------------------------------------------
// Merged gather-reduce (one dispatch).
//  blocks [0, GM_BLOCKS): movies — one wave per movie, 8 rows/instr, 2-deep.
//  blocks [GM_BLOCKS, +GU_BLOCKS): users — 8 lanes/user, 32 users/block, 4-deep.
// ---------------------------------------------------------------------------
__global__ __launch_bounds__(256) void gather_k(const int* __restrict__ off,
                                                const short* __restrict__ msg,
                                                float* __restrict__ out)
{
  if (blockIdx.x < GM_BLOCKS) {
    const int w    = blockIdx.x * 4 + (threadIdx.x >> 6);   // movie id
    const int lane = threadIdx.x & 63;
    const int sub  = lane >> 3;    // row group 0..7
    const int c8   = lane & 7;     // 16-byte chunk

    const int s0 = off[w];
    const int e1 = off[w + 1];

    float a0[8] = {0,0,0,0,0,0,0,0};
    float a1[8] = {0,0,0,0,0,0,0,0};
    float a2[8] = {0,0,0,0,0,0,0,0};
    float a3[8] = {0,0,0,0,0,0,0,0};
    int k = s0 + sub;
    for (; k + 24 < e1; k += 32) {
      const s16x8 v0 = *(const s16x8*)(msg + ((size_t)k << 6) + 8 * c8);
      const s16x8 v1 = *(const s16x8*)(msg + ((size_t)(k + 8) << 6) + 8 * c8);
      const s16x8 v2 = *(const s16x8*)(msg + ((size_t)(k + 16) << 6) + 8 * c8);
      const s16x8 v3 = *(const s16x8*)(msg + ((size_t)(k + 24) << 6) + 8 * c8);
#pragma unroll
      for (int j = 0; j < 8; ++j) {
        a0[j] += bf2f(v0[j]); a1[j] += bf2f(v1[j]);
        a2[j] += bf2f(v2[j]); a3[j] += bf2f(v3[j]);
      }
    }
    for (; k < e1; k += 8) {
      const s16x8 v0 = *(const s16x8*)(msg + ((size_t)k << 6) + 8 * c8);
#pragma unroll
      for (int j = 0; j < 8; ++j) a0[j] += bf2f(v0[j]);
    }
#pragma unroll
    for (int j = 0; j < 8; ++j) {
      a0[j] += a1[j] + a2[j] + a3[j];
      a0[j] += __shfl_xor(a0[j], 8);
      a0[j] += __shfl_xor(a0[j], 16);
      a0[j] += __shfl_xor(a0[j], 32);
    }
    if (sub == 0) {
      float* dst = out + (size_t)NU * DD + (size_t)w * DD + 8 * c8;
      float4 o0 = {a0[0], a0[1], a0[2], a0[3]};
      float4 o1 = {a0[4], a0[5], a0[6], a0[7]};
      *(float4*)dst = o0;
      *(float4*)(dst + 4) = o1;
    }
  } else {
    const int u  = (blockIdx.x - GM_BLOCKS) * 32 + (threadIdx.x >> 3);   // user id
    const int c8 = threadIdx.x & 7;

    const int s0 = off[NM + u];
    const int e1 = off[NM + u + 1];

    float a0[8] = {0,0,0,0,0,0,0,0};
    float a1[8] = {0,0,0,0,0,0,0,0};
    float a2[8] = {0,0,0,0,0,0,0,0};
    float a3[8] = {0,0,0,0,0,0,0,0};
    int k = s0;
    for (; k + 3 < e1; k += 4) {
      const s16x8 v0 = *(const s16x8*)(msg + ((size_t)k << 6) + 8 * c8);
      const s16x8 v1 = *(const s16x8*)(msg + ((size_t)(k + 1) << 6) + 8 * c8);
      const s16x8 v2 = *(const s16x8*)(msg + ((size_t)(k + 2) << 6) + 8 * c8);
      const s16x8 v3 = *(const s16x8*)(msg + ((size_t)(k + 3) << 6) + 8 * c8);
#pragma unroll
      for (int j = 0; j < 8; ++j) {
        a0[j] += bf2f(v0[j]); a1[j] += bf2f(v1[j]);
        a2[j] += bf2f(v2[j]); a3[j] += bf2f(v3[j]);
      }
    }
    for (; k < e1; ++k) {
      const s16x8 v0 = *(const s16x8*)(msg + ((size_t)k << 6) + 8 * c8);
#pragma unroll
      for (int j = 0; j < 8; ++j) a0[j] += bf2f(v0[j]);
    }
    float* dst = out + (size_t)u * DD + 8 * c8;
    float4 o0, o1;
    o0.x = a0[0] + a1[0] + a2[0] + a3[0];
    o0.y = a0[1] + a1[1] + a2[1] + a3[1];
    o0.z = a0[2] + a1[2] + a2[2] + a3[2];
    o0.w = a0[3] + a1[3] + a2[3] + a3[3];
    o1.x = a0[4] + a1[4] + a2[4] + a3[4];
    o1.y = a0[5] + a1[5] + a2[5] + a3[5];
    o1.z = a0[6] + a1[6] + a2[6] + a3[6];
    o1.w = a0[7] + a1[7] + a2[7] + a3[7];
    *(float4*)dst = o0;
    *(float4*)(dst + 4) = o1;
  }
}

// ---------------------------------------------------------------------------
// FC kernel (in-place on d_out): row -> gelu(row*ci) @ W.T + b, 16 rows/wave.
// ---------------------------------------------------------------------------
__global__ __launch_bounds__(256) void gcmc_fc(
    float* __restrict__ out,
    const float* __restrict__ user_ci, const float* __restrict__ movie_ci,
    const float* __restrict__ ufc_w, const float* __restrict__ ufc_b,
    const float* __restrict__ ifc_w, const float* __restrict__ ifc_b)
{
  const int wt   = blockIdx.x * 4 + (threadIdx.x >> 6);
  const int lane = threadIdx.x & 63;
  const int c    = lane & 15;
  const int kr   = lane >> 4;
  const bool isU = wt < (NU / 16);
  float* base        = isU ? out : out + (size_t)NU * DD;
  const float* ci    = isU ? user_ci : movie_ci;
  const float* W     = isU ? ufc_w : ifc_w;
  const float* bias  = isU ? ufc_b : ifc_b;
  const int row0 = (isU ? wt : wt - (NU / 16)) * 16;

  bf16x8 B[4][2];
#pragma unroll
  for (int t = 0; t < 4; ++t)
#pragma unroll
    for (int s = 0; s < 2; ++s)
      B[t][s] = cvt8(W + (size_t)(4 * c + t) * DD + s * 32 + kr * 8);

  const float civ = ci[row0 + c];
  const float* arow = base + (size_t)(row0 + c) * DD + kr * 8;

  bf16x8 A0, A1;
  {
    const float4 a = *(const float4*)arow;
    const float4 b = *(const float4*)(arow + 4);
    const float4 a2 = *(const float4*)(arow + 32);
    const float4 b2 = *(const float4*)(arow + 36);
    A0[0] = f2bf(gelu(a.x * civ));  A0[1] = f2bf(gelu(a.y * civ));
    A0[2] = f2bf(gelu(a.z * civ));  A0[3] = f2bf(gelu(a.w * civ));
    A0[4] = f2bf(gelu(b.x * civ));  A0[5] = f2bf(gelu(b.y * civ));
    A0[6] = f2bf(gelu(b.z * civ));  A0[7] = f2bf(gelu(b.w * civ));
    A1[0] = f2bf(gelu(a2.x * civ)); A1[1] = f2bf(gelu(a2.y * civ));
    A1[2] = f2bf(gelu(a2.z * civ)); A1[3] = f2bf(gelu(a2.w * civ));
    A1[4] = f2bf(gelu(b2.x * civ)); A1[5] = f2bf(gelu(b2.y * civ));
    A1[6] = f2bf(gelu(b2.z * civ)); A1[7] = f2bf(gelu(b2.w * civ));
  }

  f32x4 z4 = {0.f, 0.f, 0.f, 0.f};
  f32x4 C[4];
#pragma unroll
  for (int t = 0; t < 4; ++t) {
    C[t] = z4;
    C[t] = __builtin_amdgcn_mfma_f32_16x16x32_bf16(A0, B[t][0], C[t], 0, 0, 0);
    C[t] = __builtin_amdgcn_mfma_f32_16x16x32_bf16(A1, B[t][1], C[t], 0, 0, 0);
  }

  const float4 b4 = *(const float4*)(bias + 4 * c);
#pragma unroll
  for (int q = 0; q < 4; ++q) {
    const int row = row0 + kr * 4 + q;
    float4 o;
    o.x = C[0][q] + b4.x; o.y = C[1][q] + b4.y;
    o.z = C[2][q] + b4.z; o.w = C[3][q] + b4.w;
    *(float4*)(base + (size_t)row * DD + 4 * c) = o;
  }
}

extern "C" void kernel_launch(void* const* d_in, const int* in_sizes, int n_in,
                              void* d_out, int out_size, void* d_ws, size_t ws_size,
                              hipStream_t stream) {
  const int*   edges_u  = (const int*)  d_in[0];
  const int*   edges_m  = (const int*)  d_in[1];
  const float* rfeat    = (const float*)d_in[2];
  const float* W_user   = (const float*)d_in[3];
  const float* W_movie  = (const float*)d_in[4];
  const float* ps_u     = (const float*)d_in[5];
  const float* rs_u     = (const float*)d_in[6];
  const float* rw_u     = (const float*)d_in[7];
  const float* ps_m     = (const float*)d_in[8];
  const float* rs_m     = (const float*)d_in[9];
  const float* rw_m     = (const float*)d_in[10];
  const float* user_cj  = (const float*)d_in[11];
  const float* user_ci  = (const float*)d_in[12];
  const float* movie_cj = (const float*)d_in[13];
  const float* movie_ci = (const float*)d_in[14];
  const float* ufc_w    = (const float*)d_in[15];
  const float* ufc_b    = (const float*)d_in[16];
  const float* ifc_w    = (const float*)d_in[17];
  const float* ifc_b    = (const float*)d_in[18];

  float* out = (float*)d_out;

  // ---- workspace layout ----
  char* ws = (char*)d_ws;
  size_t o = 0;
  auto alloc = [&](size_t bytes) { char* p = ws + o; o += (bytes + 255) & ~(size_t)255; return p; };
  int*   cnt    = (int*)  alloc(sizeof(int) * NNODE);
  int*   off    = (int*)  alloc(sizeof(int) * (NNODE + 1));
  int*   rank_m = (int*)  alloc(sizeof(int) * NE);
  int*   rank_u = (int*)  alloc(sizeof(int) * NE);
  short* msg    = (short*)alloc(sizeof(short) * (size_t)2 * NE * DD);   // 512 MB
  (void)ws_size;

  hipMemsetAsync(cnt, 0, sizeof(int) * NNODE, stream);
  rank0_k<<<(NE / 4 + 255) / 256, 256, 0, stream>>>(edges_u, edges_m, cnt, rank_m, rank_u);
  scanoff_k<<<1, 1024, 0, stream>>>(cnt, off);

  dim3 g1(NTILE / (4 * TPW), RR);   // (250, 5) -> 1250 blocks, one generation
  gcmc_main<<<g1, 256, 0, stream>>>(edges_u, edges_m, rfeat, W_user, W_movie,
                                    ps_u, rs_u, rw_u, ps_m, rs_m, rw_m,
                                    user_cj, movie_cj, rank_m, rank_u, off, msg);

  gather_k<<<GM_BLOCKS + GU_BLOCKS, 256, 0, stream>>>(off, msg, out);

  gcmc_fc<<<(NNODE / 16) / 4, 256, 0, stream>>>(out, user_ci, movie_ci,
                                                ufc_w, ufc_b, ifc_w, ifc_b);
}

// Round 10
// 920.413 us; speedup vs baseline: 1.3674x; 1.3674x over previous
//
#include <hip/hip_runtime.h>
#include <hip/hip_bf16.h>

#define NU 100000
#define NM 20000
#define DD 64
#define RR 5
#define EE 400000
#define NE (RR * EE)            // 2,000,000 edges per direction
#define NNODE (NM + NU)         // 120,000 destination bins (movies first)
#define NTILE (EE / 16)         // 25,000 16-edge tiles per relation
#define GM_BLOCKS (NM / 4)      // 5000 movie-gather blocks (4 movies/block)
#define GU_BLOCKS (NU / 32)     // 3125 user-gather blocks (32 users/block)

typedef __attribute__((ext_vector_type(8))) short bf16x8;
typedef __attribute__((ext_vector_type(8))) short s16x8;
typedef __attribute__((ext_vector_type(4))) float f32x4;

static __device__ __forceinline__ short f2bf(float f) {
  return __builtin_bit_cast(short, __float2bfloat16(f));
}
static __device__ __forceinline__ float bf2f(short s) {
  return __builtin_bit_cast(float, ((unsigned)(unsigned short)s) << 16);
}

static __device__ __forceinline__ bf16x8 pack8(const float4 a, const float4 b) {
  bf16x8 o;
  o[0] = f2bf(a.x); o[1] = f2bf(a.y); o[2] = f2bf(a.z); o[3] = f2bf(a.w);
  o[4] = f2bf(b.x); o[5] = f2bf(b.y); o[6] = f2bf(b.z); o[7] = f2bf(b.w);
  return o;
}
static __device__ __forceinline__ bf16x8 cvt8(const float* __restrict__ p) {
  return pack8(*(const float4*)p, *(const float4*)(p + 4));
}

static __device__ __forceinline__ float sigm(float x) { return 1.f / (1.f + __expf(-x)); }
static __device__ __forceinline__ float gelu(float x) {
  return 0.5f * x * (1.f + erff(x * 0.70710678118654752f));
}

// ---------------------------------------------------------------------------
// rank0: ONE atomic pass. cnt (zeroed) -> per-edge rank within destination,
// and cnt ends up holding the per-node degree (input to scanoff).
// ---------------------------------------------------------------------------
__global__ __launch_bounds__(256) void rank0_k(const int* __restrict__ eu,
                                               const int* __restrict__ em,
                                               int* __restrict__ cnt,
                                               int* __restrict__ rank_m,
                                               int* __restrict__ rank_u) {
  const int i = (blockIdx.x * 256 + threadIdx.x) * 4;
  if (i < NE) {
    const int4 a = *(const int4*)(em + i);
    const int4 b = *(const int4*)(eu + i);
    int4 rm, ru;
    rm.x = atomicAdd(&cnt[a.x], 1);
    rm.y = atomicAdd(&cnt[a.y], 1);
    rm.z = atomicAdd(&cnt[a.z], 1);
    rm.w = atomicAdd(&cnt[a.w], 1);
    ru.x = atomicAdd(&cnt[NM + b.x], 1);
    ru.y = atomicAdd(&cnt[NM + b.y], 1);
    ru.z = atomicAdd(&cnt[NM + b.z], 1);
    ru.w = atomicAdd(&cnt[NM + b.w], 1);
    *(int4*)(rank_m + i) = rm;
    *(int4*)(rank_u + i) = ru;
  }
}

__global__ __launch_bounds__(1024) void scanoff_k(const int* __restrict__ cnt,
                                                  int* __restrict__ off) {
  __shared__ int sums[1024];
  const int t = threadIdx.x;
  const int ch = (NNODE + 1023) >> 10;    // 118
  const int b0 = t * ch;
  int s = 0;
  for (int i = 0; i < ch; ++i) { int idx = b0 + i; if (idx < NNODE) s += cnt[idx]; }
  sums[t] = s;
  __syncthreads();
  for (int d = 1; d < 1024; d <<= 1) {
    int x = (t >= d) ? sums[t - d] : 0;
    __syncthreads();
    sums[t] += x;
    __syncthreads();
  }
  int run = (t > 0) ? sums[t - 1] : 0;
  for (int i = 0; i < ch; ++i) {
    int idx = b0 + i;
    if (idx < NNODE) { off[idx] = run; run += cnt[idx]; }
  }
  if (t == 1023) off[NNODE] = sums[1023];
}

// ---------------------------------------------------------------------------
// Main fused MFMA kernel — flat schedule, single dispatch (best: 394us, R3).
// Per 16-edge tile: both directions' messages via one MFMA pass, stored (bf16)
// at slot = off[dst] + rank.  Column permutation: tile t, col c -> dim 4c+t.
// NOTE: no min-waves clamp — VGPR ~92 is what this kernel needs (R9 lesson:
// __launch_bounds__(256,5) forced VGPR 48 -> scratch spills -> FETCH 2.7x).
// ---------------------------------------------------------------------------
__global__ __launch_bounds__(256) void gcmc_main(
    const int* __restrict__ edges_u, const int* __restrict__ edges_m,
    const float* __restrict__ rfeat,
    const float* __restrict__ W_user, const float* __restrict__ W_movie,
    const float* __restrict__ ps_u, const float* __restrict__ rs_u, const float* __restrict__ rw_u,
    const float* __restrict__ ps_m, const float* __restrict__ rs_m, const float* __restrict__ rw_m,
    const float* __restrict__ user_cj, const float* __restrict__ movie_cj,
    const int* __restrict__ rank_m, const int* __restrict__ rank_u,
    const int* __restrict__ off,
    short* __restrict__ msg)
{
  const int r    = blockIdx.y;
  const int lane = threadIdx.x & 63;
  const int wid  = threadIdx.x >> 6;
  const int c    = lane & 15;
  const int kr   = lane >> 4;
  const int wtile = blockIdx.x * 4 + wid;
  if (wtile >= NTILE / 8) return;

  // ---- B fragments in registers (bf16), loaded once per wave ----
  bf16x8 Bu[4][2], Bm[4][2], Bs[2];
#pragma unroll
  for (int t = 0; t < 4; ++t) {
#pragma unroll
    for (int s = 0; s < 2; ++s) {
      Bu[t][s] = cvt8(rw_u + ((size_t)r * DD + (4 * c + t)) * DD + s * 32 + kr * 8);
      Bm[t][s] = cvt8(rw_m + ((size_t)r * DD + (4 * c + t)) * DD + s * 32 + kr * 8);
    }
  }
#pragma unroll
  for (int s = 0; s < 2; ++s) {
    if (c < 4) {
      const float* v = (c == 0 ? rs_u : c == 1 ? ps_u : c == 2 ? rs_m : ps_m)
                       + r * DD + s * 32 + kr * 8;
      Bs[s] = cvt8(v);
    } else {
      bf16x8 z = {0, 0, 0, 0, 0, 0, 0, 0};
      Bs[s] = z;
    }
  }

#pragma unroll 1
  for (int tt = 0; tt < 8; ++tt) {
    const int tile = wtile * 8 + tt;
    const int e0 = tile * 16;

    // ---- A raw loads ----
    const float* arow = rfeat + ((size_t)r * EE + e0 + c) * DD + kr * 8;
    const float4 fa0 = *(const float4*)arow;
    const float4 fa1 = *(const float4*)(arow + 4);
    const float4 fa2 = *(const float4*)(arow + 32);
    const float4 fa3 = *(const float4*)(arow + 36);

    // ---- edge / rank loads: this lane's 4 rows are consecutive -> int4 ----
    const int ebase = r * EE + e0 + kr * 4;
    const int4 eu4  = *(const int4*)(edges_u + ebase);
    const int4 em4  = *(const int4*)(edges_m + ebase);
    const int4 rm4  = *(const int4*)(rank_m + ebase);
    const int4 ru4  = *(const int4*)(rank_u + ebase);
    const int eus[4] = {eu4.x, eu4.y, eu4.z, eu4.w};
    const int ems[4] = {em4.x, em4.y, em4.z, em4.w};
    const int rms[4] = {rm4.x, rm4.y, rm4.z, rm4.w};
    const int rus[4] = {ru4.x, ru4.y, ru4.z, ru4.w};

    // ---- dependent gathers, all issued up-front ----
    int slm[4], slu[4];
    float cju[4], cjm[4];
    float4 hu[4], hm[4];
#pragma unroll
    for (int q = 0; q < 4; ++q) {
      slm[q] = off[ems[q]] + rms[q];
      slu[q] = off[NM + eus[q]] + rus[q];
      cju[q] = user_cj[eus[q]];
      cjm[q] = movie_cj[ems[q]];
      hu[q]  = *(const float4*)(W_user  + ((size_t)r * NU + eus[q]) * DD + 4 * c);
      hm[q]  = *(const float4*)(W_movie + ((size_t)r * NM + ems[q]) * DD + 4 * c);
    }

    // ---- MFMA ----
    const bf16x8 A0 = pack8(fa0, fa1);
    const bf16x8 A1 = pack8(fa2, fa3);
    f32x4 z4 = {0.f, 0.f, 0.f, 0.f};
    f32x4 Cu[4], Cm[4], Cs;
#pragma unroll
    for (int t = 0; t < 4; ++t) { Cu[t] = z4; Cm[t] = z4; }
    Cs = z4;
#pragma unroll
    for (int t = 0; t < 4; ++t) {
      Cu[t] = __builtin_amdgcn_mfma_f32_16x16x32_bf16(A0, Bu[t][0], Cu[t], 0, 0, 0);
      Cu[t] = __builtin_amdgcn_mfma_f32_16x16x32_bf16(A1, Bu[t][1], Cu[t], 0, 0, 0);
      Cm[t] = __builtin_amdgcn_mfma_f32_16x16x32_bf16(A0, Bm[t][0], Cm[t], 0, 0, 0);
      Cm[t] = __builtin_amdgcn_mfma_f32_16x16x32_bf16(A1, Bm[t][1], Cm[t], 0, 0, 0);
    }
    Cs = __builtin_amdgcn_mfma_f32_16x16x32_bf16(A0, Bs[0], Cs, 0, 0, 0);
    Cs = __builtin_amdgcn_mfma_f32_16x16x32_bf16(A1, Bs[1], Cs, 0, 0, 0);

    // ---- combine + store ----
#pragma unroll
    for (int q = 0; q < 4; ++q) {
      const int src = (lane & 48);
      const float su = __shfl(Cs[q], src);
      const float pu = __shfl(Cs[q], src | 1);
      const float sm = __shfl(Cs[q], src | 2);
      const float pm = __shfl(Cs[q], src | 3);
      const float sgu = sigm(su), pau = sigm(pu);
      const float sgm_ = sigm(sm), pam = sigm(pm);

      short4 vm, vu;
      vm.x = f2bf((hu[q].x * pau + Cu[0][q] * sgu) * cju[q]);
      vm.y = f2bf((hu[q].y * pau + Cu[1][q] * sgu) * cju[q]);
      vm.z = f2bf((hu[q].z * pau + Cu[2][q] * sgu) * cju[q]);
      vm.w = f2bf((hu[q].w * pau + Cu[3][q] * sgu) * cju[q]);
      vu.x = f2bf((hm[q].x * pam + Cm[0][q] * sgm_) * cjm[q]);
      vu.y = f2bf((hm[q].y * pam + Cm[1][q] * sgm_) * cjm[q]);
      vu.z = f2bf((hm[q].z * pam + Cm[2][q] * sgm_) * cjm[q]);
      vu.w = f2bf((hm[q].w * pam + Cm[3][q] * sgm_) * cjm[q]);

      *(short4*)(msg + ((size_t)slm[q] << 6) + 4 * c) = vm;
      *(short4*)(msg + ((size_t)slu[q] << 6) + 4 * c) = vu;
    }
  }
}

// ---------------------------------------------------------------------------
// Merged gather-reduce (one dispatch).
//  blocks [0, GM_BLOCKS): movies — one wave per movie, 8 rows/instr, 4-deep.
//  blocks [GM_BLOCKS, +GU_BLOCKS): users — 8 lanes/user, 32 users/block, 4-deep.
// ---------------------------------------------------------------------------
__global__ __launch_bounds__(256) void gather_k(const int* __restrict__ off,
                                                const short* __restrict__ msg,
                                                float* __restrict__ out)
{
  if (blockIdx.x < GM_BLOCKS) {
    const int w    = blockIdx.x * 4 + (threadIdx.x >> 6);   // movie id
    const int lane = threadIdx.x & 63;
    const int sub  = lane >> 3;    // row group 0..7
    const int c8   = lane & 7;     // 16-byte chunk

    const int s0 = off[w];
    const int e1 = off[w + 1];

    float a0[8] = {0,0,0,0,0,0,0,0};
    float a1[8] = {0,0,0,0,0,0,0,0};
    float a2[8] = {0,0,0,0,0,0,0,0};
    float a3[8] = {0,0,0,0,0,0,0,0};
    int k = s0 + sub;
    for (; k + 24 < e1; k += 32) {
      const s16x8 v0 = *(const s16x8*)(msg + ((size_t)k << 6) + 8 * c8);
      const s16x8 v1 = *(const s16x8*)(msg + ((size_t)(k + 8) << 6) + 8 * c8);
      const s16x8 v2 = *(const s16x8*)(msg + ((size_t)(k + 16) << 6) + 8 * c8);
      const s16x8 v3 = *(const s16x8*)(msg + ((size_t)(k + 24) << 6) + 8 * c8);
#pragma unroll
      for (int j = 0; j < 8; ++j) {
        a0[j] += bf2f(v0[j]); a1[j] += bf2f(v1[j]);
        a2[j] += bf2f(v2[j]); a3[j] += bf2f(v3[j]);
      }
    }
    for (; k < e1; k += 8) {
      const s16x8 v0 = *(const s16x8*)(msg + ((size_t)k << 6) + 8 * c8);
#pragma unroll
      for (int j = 0; j < 8; ++j) a0[j] += bf2f(v0[j]);
    }
#pragma unroll
    for (int j = 0; j < 8; ++j) {
      a0[j] += a1[j] + a2[j] + a3[j];
      a0[j] += __shfl_xor(a0[j], 8);
      a0[j] += __shfl_xor(a0[j], 16);
      a0[j] += __shfl_xor(a0[j], 32);
    }
    if (sub == 0) {
      float* dst = out + (size_t)NU * DD + (size_t)w * DD + 8 * c8;
      float4 o0 = {a0[0], a0[1], a0[2], a0[3]};
      float4 o1 = {a0[4], a0[5], a0[6], a0[7]};
      *(float4*)dst = o0;
      *(float4*)(dst + 4) = o1;
    }
  } else {
    const int u  = (blockIdx.x - GM_BLOCKS) * 32 + (threadIdx.x >> 3);   // user id
    const int c8 = threadIdx.x & 7;

    const int s0 = off[NM + u];
    const int e1 = off[NM + u + 1];

    float a0[8] = {0,0,0,0,0,0,0,0};
    float a1[8] = {0,0,0,0,0,0,0,0};
    float a2[8] = {0,0,0,0,0,0,0,0};
    float a3[8] = {0,0,0,0,0,0,0,0};
    int k = s0;
    for (; k + 3 < e1; k += 4) {
      const s16x8 v0 = *(const s16x8*)(msg + ((size_t)k << 6) + 8 * c8);
      const s16x8 v1 = *(const s16x8*)(msg + ((size_t)(k + 1) << 6) + 8 * c8);
      const s16x8 v2 = *(const s16x8*)(msg + ((size_t)(k + 2) << 6) + 8 * c8);
      const s16x8 v3 = *(const s16x8*)(msg + ((size_t)(k + 3) << 6) + 8 * c8);
#pragma unroll
      for (int j = 0; j < 8; ++j) {
        a0[j] += bf2f(v0[j]); a1[j] += bf2f(v1[j]);
        a2[j] += bf2f(v2[j]); a3[j] += bf2f(v3[j]);
      }
    }
    for (; k < e1; ++k) {
      const s16x8 v0 = *(const s16x8*)(msg + ((size_t)k << 6) + 8 * c8);
#pragma unroll
      for (int j = 0; j < 8; ++j) a0[j] += bf2f(v0[j]);
    }
    float* dst = out + (size_t)u * DD + 8 * c8;
    float4 o0, o1;
    o0.x = a0[0] + a1[0] + a2[0] + a3[0];
    o0.y = a0[1] + a1[1] + a2[1] + a3[1];
    o0.z = a0[2] + a1[2] + a2[2] + a3[2];
    o0.w = a0[3] + a1[3] + a2[3] + a3[3];
    o1.x = a0[4] + a1[4] + a2[4] + a3[4];
    o1.y = a0[5] + a1[5] + a2[5] + a3[5];
    o1.z = a0[6] + a1[6] + a2[6] + a3[6];
    o1.w = a0[7] + a1[7] + a2[7] + a3[7];
    *(float4*)dst = o0;
    *(float4*)(dst + 4) = o1;
  }
}

// ---------------------------------------------------------------------------
// FC kernel (in-place on d_out): row -> gelu(row*ci) @ W.T + b, 16 rows/wave.
// ---------------------------------------------------------------------------
__global__ __launch_bounds__(256) void gcmc_fc(
    float* __restrict__ out,
    const float* __restrict__ user_ci, const float* __restrict__ movie_ci,
    const float* __restrict__ ufc_w, const float* __restrict__ ufc_b,
    const float* __restrict__ ifc_w, const float* __restrict__ ifc_b)
{
  const int wt   = blockIdx.x * 4 + (threadIdx.x >> 6);
  const int lane = threadIdx.x & 63;
  const int c    = lane & 15;
  const int kr   = lane >> 4;
  const bool isU = wt < (NU / 16);
  float* base        = isU ? out : out + (size_t)NU * DD;
  const float* ci    = isU ? user_ci : movie_ci;
  const float* W     = isU ? ufc_w : ifc_w;
  const float* bias  = isU ? ufc_b : ifc_b;
  const int row0 = (isU ? wt : wt - (NU / 16)) * 16;

  bf16x8 B[4][2];
#pragma unroll
  for (int t = 0; t < 4; ++t)
#pragma unroll
    for (int s = 0; s < 2; ++s)
      B[t][s] = cvt8(W + (size_t)(4 * c + t) * DD + s * 32 + kr * 8);

  const float civ = ci[row0 + c];
  const float* arow = base + (size_t)(row0 + c) * DD + kr * 8;

  bf16x8 A0, A1;
  {
    const float4 a = *(const float4*)arow;
    const float4 b = *(const float4*)(arow + 4);
    const float4 a2 = *(const float4*)(arow + 32);
    const float4 b2 = *(const float4*)(arow + 36);
    A0[0] = f2bf(gelu(a.x * civ));  A0[1] = f2bf(gelu(a.y * civ));
    A0[2] = f2bf(gelu(a.z * civ));  A0[3] = f2bf(gelu(a.w * civ));
    A0[4] = f2bf(gelu(b.x * civ));  A0[5] = f2bf(gelu(b.y * civ));
    A0[6] = f2bf(gelu(b.z * civ));  A0[7] = f2bf(gelu(b.w * civ));
    A1[0] = f2bf(gelu(a2.x * civ)); A1[1] = f2bf(gelu(a2.y * civ));
    A1[2] = f2bf(gelu(a2.z * civ)); A1[3] = f2bf(gelu(a2.w * civ));
    A1[4] = f2bf(gelu(b2.x * civ)); A1[5] = f2bf(gelu(b2.y * civ));
    A1[6] = f2bf(gelu(b2.z * civ)); A1[7] = f2bf(gelu(b2.w * civ));
  }

  f32x4 z4 = {0.f, 0.f, 0.f, 0.f};
  f32x4 C[4];
#pragma unroll
  for (int t = 0; t < 4; ++t) {
    C[t] = z4;
    C[t] = __builtin_amdgcn_mfma_f32_16x16x32_bf16(A0, B[t][0], C[t], 0, 0, 0);
    C[t] = __builtin_amdgcn_mfma_f32_16x16x32_bf16(A1, B[t][1], C[t], 0, 0, 0);
  }

  const float4 b4 = *(const float4*)(bias + 4 * c);
#pragma unroll
  for (int q = 0; q < 4; ++q) {
    const int row = row0 + kr * 4 + q;
    float4 o;
    o.x = C[0][q] + b4.x; o.y = C[1][q] + b4.y;
    o.z = C[2][q] + b4.z; o.w = C[3][q] + b4.w;
    *(float4*)(base + (size_t)row * DD + 4 * c) = o;
  }
}

extern "C" void kernel_launch(void* const* d_in, const int* in_sizes, int n_in,
                              void* d_out, int out_size, void* d_ws, size_t ws_size,
                              hipStream_t stream) {
  const int*   edges_u  = (const int*)  d_in[0];
  const int*   edges_m  = (const int*)  d_in[1];
  const float* rfeat    = (const float*)d_in[2];
  const float* W_user   = (const float*)d_in[3];
  const float* W_movie  = (const float*)d_in[4];
  const float* ps_u     = (const float*)d_in[5];
  const float* rs_u     = (const float*)d_in[6];
  const float* rw_u     = (const float*)d_in[7];
  const float* ps_m     = (const float*)d_in[8];
  const float* rs_m     = (const float*)d_in[9];
  const float* rw_m     = (const float*)d_in[10];
  const float* user_cj  = (const float*)d_in[11];
  const float* user_ci  = (const float*)d_in[12];
  const float* movie_cj = (const float*)d_in[13];
  const float* movie_ci = (const float*)d_in[14];
  const float* ufc_w    = (const float*)d_in[15];
  const float* ufc_b    = (const float*)d_in[16];
  const float* ifc_w    = (const float*)d_in[17];
  const float* ifc_b    = (const float*)d_in[18];

  float* out = (float*)d_out;

  // ---- workspace layout ----
  char* ws = (char*)d_ws;
  size_t o = 0;
  auto alloc = [&](size_t bytes) { char* p = ws + o; o += (bytes + 255) & ~(size_t)255; return p; };
  int*   cnt    = (int*)  alloc(sizeof(int) * NNODE);
  int*   off    = (int*)  alloc(sizeof(int) * (NNODE + 1));
  int*   rank_m = (int*)  alloc(sizeof(int) * NE);
  int*   rank_u = (int*)  alloc(sizeof(int) * NE);
  short* msg    = (short*)alloc(sizeof(short) * (size_t)2 * NE * DD);   // 512 MB
  (void)ws_size;

  hipMemsetAsync(cnt, 0, sizeof(int) * NNODE, stream);
  rank0_k<<<(NE / 4 + 255) / 256, 256, 0, stream>>>(edges_u, edges_m, cnt, rank_m, rank_u);
  scanoff_k<<<1, 1024, 0, stream>>>(cnt, off);

  dim3 g1((NTILE / 8 + 3) / 4, RR);   // (782, 5)
  gcmc_main<<<g1, 256, 0, stream>>>(edges_u, edges_m, rfeat, W_user, W_movie,
                                    ps_u, rs_u, rw_u, ps_m, rs_m, rw_m,
                                    user_cj, movie_cj, rank_m, rank_u, off, msg);

  gather_k<<<GM_BLOCKS + GU_BLOCKS, 256, 0, stream>>>(off, msg, out);

  gcmc_fc<<<(NNODE / 16) / 4, 256, 0, stream>>>(out, user_ci, movie_ci,
                                                ufc_w, ufc_b, ifc_w, ifc_b);
}